// Round 4
// baseline (208.393 us; speedup 1.0000x reference)
//
#include <hip/hip_runtime.h>
#include <stdint.h>

#define B_ 8
#define C_ 256
#define N_ 4096
#define LOG2E 1.44269504088896f
#define NSHIFT_L2E (-14.0f * 1.44269504088896f)   // exp(s-14) = exp2(s*log2e - 14*log2e)

typedef _Float16 half8 __attribute__((ext_vector_type(8)));
typedef _Float16 half4 __attribute__((ext_vector_type(4)));
typedef __fp16  fp16x2 __attribute__((ext_vector_type(2)));
typedef float floatx4 __attribute__((ext_vector_type(4)));

// ---------------- K0: weights -> fragment-ordered fp16 Whf + Bh -------------
__global__ __launch_bounds__(256) void k_wprep(const float* __restrict__ wq, const float* __restrict__ bq,
                                               const float* __restrict__ wk, const float* __restrict__ bk,
                                               const float* __restrict__ wv, const float* __restrict__ bv,
                                               _Float16* __restrict__ Whf, float* __restrict__ Bh) {
    int r = blockIdx.x;   // n: 0..319
    int t = threadIdx.x;  // k: 0..255
    const float* src;
    float bias;
    if (r < 32)      { src = wq + r * 256;        bias = bq[r]; }
    else if (r < 64) { src = wk + (r - 32) * 256; bias = bk[r - 32]; }
    else             { src = wv + (r - 64) * 256; bias = bv[r - 64]; }
    Whf[(t >> 3) * 2560 + r * 8 + (t & 7)] = (_Float16)src[t];
    if (t == 0) Bh[r] = bias;
}

// ---------------- K1: fused transpose + projection GEMM ---------------------
//   Kf[b][i>>5][k>>3][i&31][k&7]  (k = n)   PRE-SCALED by LOG2E      2 MB
//   Qf[b][j>>5][k>>3][j&31][k&7]  (k = n-32)                         2 MB
//   Vf[b][i>>4][c][i&15]          (c = n-64)                        16.8 MB
__global__ __launch_bounds__(256) void k_proj(const float* __restrict__ x,
                                              const _Float16* __restrict__ Whf,
                                              const float* __restrict__ Bh,
                                              _Float16* __restrict__ Kf,
                                              _Float16* __restrict__ Qf,
                                              _Float16* __restrict__ Vf) {
    __shared__ float xtile[64 * 65];                                 // 16,640 B
    __shared__ _Float16 As[64 * 264] __attribute__((aligned(16)));   // 33,792 B
    int id = blockIdx.x;
    int b  = id & 7;          // XCD-local batch
    int i0 = (id >> 3) * 64;
    int t = threadIdx.x;
    int w = t >> 6, lane = t & 63, col = lane & 15, q = lane >> 4;
    const float* xb = x + (size_t)b * C_ * N_ + i0;
    for (int cc = 0; cc < 4; ++cc) {
        int cr = t >> 4;
        int ip = (t & 15) * 4;
#pragma unroll
        for (int k = 0; k < 4; ++k)
            *(float4*)&xtile[(cr + 16 * k) * 65 + ip] =
                *(const float4*)&xb[(size_t)(cc * 64 + cr + 16 * k) * N_ + ip];
        __syncthreads();
        int i = t & 63, cb2 = (t >> 6) * 16;
        float v[16];
#pragma unroll
        for (int k = 0; k < 16; ++k) v[k] = xtile[(cb2 + k) * 65 + i];
        half8 h0, h1;
#pragma unroll
        for (int k = 0; k < 8; ++k) { h0[k] = (_Float16)v[k]; h1[k] = (_Float16)v[8 + k]; }
        *(half8*)&As[i * 264 + cc * 64 + cb2] = h0;
        *(half8*)&As[i * 264 + cc * 64 + cb2 + 8] = h1;
        __syncthreads();
    }
    floatx4 acc[4][5];
#pragma unroll
    for (int mt = 0; mt < 4; ++mt)
#pragma unroll
        for (int nt = 0; nt < 5; ++nt) acc[mt][nt] = (floatx4){0.f, 0.f, 0.f, 0.f};
    for (int kc = 0; kc < 8; ++kc) {
        half8 a[4], bf[5];
#pragma unroll
        for (int nt = 0; nt < 5; ++nt)
            bf[nt] = *(const half8*)&Whf[(kc * 4 + q) * 2560 + (w * 80 + nt * 16 + col) * 8];
#pragma unroll
        for (int mt = 0; mt < 4; ++mt)
            a[mt] = *(const half8*)&As[(mt * 16 + col) * 264 + kc * 32 + q * 8];
#pragma unroll
        for (int mt = 0; mt < 4; ++mt)
#pragma unroll
            for (int nt = 0; nt < 5; ++nt)
                acc[mt][nt] = __builtin_amdgcn_mfma_f32_16x16x32_f16(a[mt], bf[nt], acc[mt][nt], 0, 0, 0);
    }
#pragma unroll
    for (int nt = 0; nt < 5; ++nt) {
        int n = w * 80 + nt * 16 + col;
        float bias = Bh[n];
        if (n < 32) {
#pragma unroll
            for (int mt = 0; mt < 4; ++mt)
#pragma unroll
                for (int r = 0; r < 4; ++r) {
                    int i = i0 + mt * 16 + q * 4 + r;
                    Kf[((((size_t)b * 128 + (i >> 5)) * 4 + (n >> 3)) * 32 + (i & 31)) * 8 + (n & 7)]
                        = (_Float16)((acc[mt][nt][r] + bias) * LOG2E);
                }
        } else if (n < 64) {
            int n2 = n - 32;
#pragma unroll
            for (int mt = 0; mt < 4; ++mt)
#pragma unroll
                for (int r = 0; r < 4; ++r) {
                    int j = i0 + mt * 16 + q * 4 + r;
                    Qf[((((size_t)b * 128 + (j >> 5)) * 4 + (n2 >> 3)) * 32 + (j & 31)) * 8 + (n2 & 7)]
                        = (_Float16)(acc[mt][nt][r] + bias);
                }
        } else {
            int c = n - 64;
#pragma unroll
            for (int mt = 0; mt < 4; ++mt) {
                int ib = (i0 >> 4) + mt;
                half4 v4;
#pragma unroll
                for (int r = 0; r < 4; ++r) v4[r] = (_Float16)(acc[mt][nt][r] + bias);
                *(half4*)&Vf[(((size_t)b * 256 + ib) * 256 + c) * 16 + q * 4] = v4;
            }
        }
    }
}

// ---------------- K2: fused attention v7 ------------------------------------
// Block = c256 x j128 tile, 8 waves, 1 block/CU (grid 256).
// Wave (cs=w&3, jh=w>>2): PV output = c-strip 64 x j-half 64 (acc[4][4], 32
// MFMA/step); S role: j-tile w*16 x all 64 i (4 MFMA/step). Halves per-work
// LDS reads vs v6 (each wave reads only its 8 KB j-half of Ps, 4x c-reuse).
// Ps = 128 x 64 halfs, XOR-swizzled rows (chunk ^= j&7), double-buffered.
// Relaxed lgkm-only barrier; Kf pre-scaled by LOG2E; NSHIFT in MFMA C-init.
#define PS_HALF 8192  /* halfs per Ps buffer (128 x 64, swizzled, 16 KB) */

#define ATTN_SBLK(T, AK, WOFF)                                                    \
    {                                                                             \
        floatx4 s = __builtin_amdgcn_mfma_f32_16x16x32_f16(AK, bq, cns, 0, 0, 0); \
        float p0 = exp2f(s[0]);                                                   \
        float p1 = exp2f(s[1]);                                                   \
        float p2 = exp2f(s[2]);                                                   \
        float p3 = exp2f(s[3]);                                                   \
        lacc += (p0 + p1) + (p2 + p3);                                            \
        union { fp16x2 v; uint32_t u; } plo, phi;                                 \
        plo.v = __builtin_amdgcn_cvt_pkrtz(p0, p1);                               \
        phi.v = __builtin_amdgcn_cvt_pkrtz(p2, p3);                               \
        uint2 pw; pw.x = plo.u; pw.y = phi.u;                                     \
        *(uint2*)&PsF[(WOFF) + wo##T] = pw;                                       \
    }

#define ATTN_STEP(IT, VCUR, VNXT, ROFF, WOFF)                                     \
    {                                                                             \
        if ((IT) < 63) {                                                          \
            _Pragma("unroll")                                                     \
            for (int ct = 0; ct < 4; ++ct) {                                      \
                VNXT[ct * 2 + 0] = *(const half8*)(pV0 + ct * 256);               \
                VNXT[ct * 2 + 1] = *(const half8*)(pV1 + ct * 256);               \
            }                                                                     \
            pV0 += 16384; pV1 += 16384;                                           \
            aK0 = *(const half8*)(pK);                                            \
            aK1 = *(const half8*)(pK + 128);                                      \
            aK2 = *(const half8*)(pK + 1024);                                     \
            aK3 = *(const half8*)(pK + 1152);                                     \
            pK += 2048;                                                           \
        }                                                                         \
        _Pragma("unroll")                                                         \
        for (int kk = 0; kk < 2; ++kk) {                                          \
            half8 bfr[4];                                                         \
            _Pragma("unroll")                                                     \
            for (int jt = 0; jt < 4; ++jt)                                        \
                bfr[jt] = *(const half8*)&PsF[(ROFF) + jt * 1024 + (kk ? ro1 : ro0)]; \
            _Pragma("unroll")                                                     \
            for (int ct = 0; ct < 4; ++ct)                                        \
                _Pragma("unroll")                                                 \
                for (int jt = 0; jt < 4; ++jt)                                    \
                    acc[ct][jt] = __builtin_amdgcn_mfma_f32_16x16x32_f16(         \
                        VCUR[ct * 2 + kk], bfr[jt], acc[ct][jt], 0, 0, 0);        \
        }                                                                         \
        if ((IT) < 63) {                                                          \
            ATTN_SBLK(0, aK0, WOFF)                                               \
            ATTN_SBLK(1, aK1, WOFF)                                               \
            ATTN_SBLK(2, aK2, WOFF)                                               \
            ATTN_SBLK(3, aK3, WOFF)                                               \
        }                                                                         \
        asm volatile("s_waitcnt lgkmcnt(0)\n\ts_barrier" ::: "memory");           \
    }

__global__ __launch_bounds__(512, 2) void k_attn(const _Float16* __restrict__ Kf,
                                                 const _Float16* __restrict__ Qf,
                                                 const _Float16* __restrict__ Vf,
                                                 const float* __restrict__ x,
                                                 const float* __restrict__ gptr,
                                                 float* __restrict__ out) {
    __shared__ _Float16 PsF[2 * PS_HALF] __attribute__((aligned(16)));  // 32,768 B
    __shared__ float Lp[128];
    int id = blockIdx.x;
    int b  = id & 7;            // XCD-local batch
    int j0 = (id >> 3) * 128;
    int t = threadIdx.x;
    int w = t >> 6, lane = t & 63, col = lane & 15, q = lane >> 4;
    int cs = w & 3, jh = w >> 2;     // PV role: c-strip 64, j-half 64
    const _Float16* Kfb = Kf + (size_t)b * 131072;
    const _Float16* Qfb = Qf + (size_t)b * 131072;
    const _Float16* Vfb = Vf + (size_t)b * 1048576;
    // ---- per-lane invariant pointers / offsets
    const _Float16* pK  = Kfb + q * 256 + col * 8;       // +t in {0,128,1024,1152}, +it*2048
    const _Float16* pV0 = Vfb + ((q >> 1) * 256 + cs * 64 + col) * 16 + (q & 1) * 8;  // +ct*256, +it*16384
    const _Float16* pV1 = pV0 + 8192;                    // kk=1
    // ---- swizzled Ps offsets (half units; row = 64 halfs = 128 B, chunk = 8 halfs)
    // read  (PV B-frag): row = jh*64 + jt*16 + col, chunk = (kk*4 + q) ^ (col&7)
    // write (S uint2)  : row = w*16 + col, chunk = (t*2 + (q>>1)) ^ (col&7)
    const int cswz = col & 7;
    const int ro0 = (jh * 64 + col) * 64 + ((q ^ cswz) << 3);   // kk = 0 (+jt*1024)
    const int ro1 = ro0 ^ 32;                                   // kk = 1 (chunk bit2)
    const int wo0 = (w * 16 + col) * 64 + (((0 + (q >> 1)) ^ cswz) << 3) + (q & 1) * 4;
    const int wo1 = (w * 16 + col) * 64 + (((2 + (q >> 1)) ^ cswz) << 3) + (q & 1) * 4;
    const int wo2 = (w * 16 + col) * 64 + (((4 + (q >> 1)) ^ cswz) << 3) + (q & 1) * 4;
    const int wo3 = (w * 16 + col) * 64 + (((6 + (q >> 1)) ^ cswz) << 3) + (q & 1) * 4;
    const floatx4 cns = {NSHIFT_L2E, NSHIFT_L2E, NSHIFT_L2E, NSHIFT_L2E};
    floatx4 acc[4][4];
#pragma unroll
    for (int ct = 0; ct < 4; ++ct)
#pragma unroll
        for (int jt = 0; jt < 4; ++jt) acc[ct][jt] = (floatx4){0.f, 0.f, 0.f, 0.f};
    float lacc = 0.f;
    half8 vA[8], vB[8], aK0, aK1, aK2, aK3;
    // ---- prologue: issue V(0), K(0), Q; compute S(0) -> buf0
#pragma unroll
    for (int ct = 0; ct < 4; ++ct) {
        vA[ct * 2 + 0] = *(const half8*)(pV0 + ct * 256);
        vA[ct * 2 + 1] = *(const half8*)(pV1 + ct * 256);
    }
    pV0 += 16384; pV1 += 16384;
    aK0 = *(const half8*)(pK);
    aK1 = *(const half8*)(pK + 128);
    aK2 = *(const half8*)(pK + 1024);
    aK3 = *(const half8*)(pK + 1152);
    pK += 2048;
    int jj = j0 + w * 16;
    half8 bq = *(const half8*)&Qfb[(((jj >> 5) * 4 + q) * 256 + ((jj & 31) + col) * 8)];
    ATTN_SBLK(0, aK0, 0)
    ATTN_SBLK(1, aK1, 0)
    ATTN_SBLK(2, aK2, 0)
    ATTN_SBLK(3, aK3, 0)
    asm volatile("s_waitcnt lgkmcnt(0)\n\ts_barrier" ::: "memory");
    // ---- main loop: 64 steps, unrolled by 2 (one relaxed barrier per step)
    for (int m = 0; m < 32; ++m) {
        int it = m * 2;
        ATTN_STEP(it,     vA, vB, 0,       PS_HALF)
        ATTN_STEP(it + 1, vB, vA, PS_HALF, 0)
    }
    // ---- l finalize (each j-column owned by exactly one wave)
    lacc += __shfl_xor(lacc, 16, 64);
    lacc += __shfl_xor(lacc, 32, 64);
    if (lane < 16) Lp[w * 16 + lane] = lacc;
    __syncthreads();
    float gamma = gptr[0];
    const float* xb = x + (size_t)b * C_ * N_;
    float* ob = out + (size_t)b * C_ * N_;
#pragma unroll
    for (int jt = 0; jt < 4; ++jt) {
        int jl = jh * 64 + jt * 16 + col;
        float li = 1.0f / Lp[jl];
        int j = j0 + jl;
#pragma unroll
        for (int ct = 0; ct < 4; ++ct)
#pragma unroll
            for (int r = 0; r < 4; ++r) {
                int c = cs * 64 + ct * 16 + q * 4 + r;
                size_t off = (size_t)c * N_ + j;
                ob[off] = gamma * acc[ct][jt][r] * li + xb[off];
            }
    }
}

extern "C" void kernel_launch(void* const* d_in, const int* in_sizes, int n_in,
                              void* d_out, int out_size, void* d_ws, size_t ws_size,
                              hipStream_t stream) {
    const float* x  = (const float*)d_in[0];
    const float* wq = (const float*)d_in[1];
    const float* bq = (const float*)d_in[2];
    const float* wk = (const float*)d_in[3];
    const float* bk = (const float*)d_in[4];
    const float* wv = (const float*)d_in[5];
    const float* bv = (const float*)d_in[6];
    const float* gm = (const float*)d_in[7];
    float* out = (float*)d_out;
    char* ws = (char*)d_ws;
    // workspace layout (~21.1 MB)
    _Float16* Vf  = (_Float16*)ws;                    // 16,777,216 B
    _Float16* Kf  = (_Float16*)(ws + 16777216);       //  2,097,152 B
    _Float16* Qf  = (_Float16*)(ws + 18874368);       //  2,097,152 B
    _Float16* Whf = (_Float16*)(ws + 20971520);       //    163,840 B
    float*    Bh  = (float*)(ws + 21135360);          //      1,280 B

    k_wprep<<<dim3(320), 256, 0, stream>>>(wq, bq, wk, bk, wv, bv, Whf, Bh);
    k_proj<<<dim3(512), 256, 0, stream>>>(x, Whf, Bh, Kf, Qf, Vf);
    k_attn<<<dim3(256), 512, 0, stream>>>(Kf, Qf, Vf, x, gm, out);
}

// Round 5
// 190.910 us; speedup vs baseline: 1.0916x; 1.0916x over previous
//
#include <hip/hip_runtime.h>
#include <stdint.h>

#define B_ 8
#define C_ 256
#define N_ 4096
#define LOG2E 1.44269504088896f
#define NSHIFT_L2E (-14.0f * 1.44269504088896f)   // exp(s-14) = exp2(s*log2e - 14*log2e)

typedef _Float16 half8 __attribute__((ext_vector_type(8)));
typedef _Float16 half4 __attribute__((ext_vector_type(4)));
typedef __fp16  fp16x2 __attribute__((ext_vector_type(2)));
typedef float floatx4 __attribute__((ext_vector_type(4)));

// ---------------- K0: weights -> fragment-ordered fp16 Whf + Bh -------------
__global__ __launch_bounds__(256) void k_wprep(const float* __restrict__ wq, const float* __restrict__ bq,
                                               const float* __restrict__ wk, const float* __restrict__ bk,
                                               const float* __restrict__ wv, const float* __restrict__ bv,
                                               _Float16* __restrict__ Whf, float* __restrict__ Bh) {
    int r = blockIdx.x;   // n: 0..319
    int t = threadIdx.x;  // k: 0..255
    const float* src;
    float bias;
    if (r < 32)      { src = wq + r * 256;        bias = bq[r]; }
    else if (r < 64) { src = wk + (r - 32) * 256; bias = bk[r - 32]; }
    else             { src = wv + (r - 64) * 256; bias = bv[r - 64]; }
    Whf[(t >> 3) * 2560 + r * 8 + (t & 7)] = (_Float16)src[t];
    if (t == 0) Bh[r] = bias;
}

// ---------------- K1: fused transpose + projection GEMM ---------------------
//   Kf[b][i>>5][k>>3][i&31][k&7]  (k = n)   PRE-SCALED by LOG2E      2 MB
//   Qf[b][j>>5][k>>3][j&31][k&7]  (k = n-32)                         2 MB
//   Vf[b][i>>4][c][i&15]          (c = n-64)                        16.8 MB
__global__ __launch_bounds__(256) void k_proj(const float* __restrict__ x,
                                              const _Float16* __restrict__ Whf,
                                              const float* __restrict__ Bh,
                                              _Float16* __restrict__ Kf,
                                              _Float16* __restrict__ Qf,
                                              _Float16* __restrict__ Vf) {
    __shared__ float xtile[64 * 65];                                 // 16,640 B
    __shared__ _Float16 As[64 * 264] __attribute__((aligned(16)));   // 33,792 B
    int id = blockIdx.x;
    int b  = id & 7;          // XCD-local batch
    int i0 = (id >> 3) * 64;
    int t = threadIdx.x;
    int w = t >> 6, lane = t & 63, col = lane & 15, q = lane >> 4;
    const float* xb = x + (size_t)b * C_ * N_ + i0;
    for (int cc = 0; cc < 4; ++cc) {
        int cr = t >> 4;
        int ip = (t & 15) * 4;
#pragma unroll
        for (int k = 0; k < 4; ++k)
            *(float4*)&xtile[(cr + 16 * k) * 65 + ip] =
                *(const float4*)&xb[(size_t)(cc * 64 + cr + 16 * k) * N_ + ip];
        __syncthreads();
        int i = t & 63, cb2 = (t >> 6) * 16;
        float v[16];
#pragma unroll
        for (int k = 0; k < 16; ++k) v[k] = xtile[(cb2 + k) * 65 + i];
        half8 h0, h1;
#pragma unroll
        for (int k = 0; k < 8; ++k) { h0[k] = (_Float16)v[k]; h1[k] = (_Float16)v[8 + k]; }
        *(half8*)&As[i * 264 + cc * 64 + cb2] = h0;
        *(half8*)&As[i * 264 + cc * 64 + cb2 + 8] = h1;
        __syncthreads();
    }
    floatx4 acc[4][5];
#pragma unroll
    for (int mt = 0; mt < 4; ++mt)
#pragma unroll
        for (int nt = 0; nt < 5; ++nt) acc[mt][nt] = (floatx4){0.f, 0.f, 0.f, 0.f};
    for (int kc = 0; kc < 8; ++kc) {
        half8 a[4], bf[5];
#pragma unroll
        for (int nt = 0; nt < 5; ++nt)
            bf[nt] = *(const half8*)&Whf[(kc * 4 + q) * 2560 + (w * 80 + nt * 16 + col) * 8];
#pragma unroll
        for (int mt = 0; mt < 4; ++mt)
            a[mt] = *(const half8*)&As[(mt * 16 + col) * 264 + kc * 32 + q * 8];
#pragma unroll
        for (int mt = 0; mt < 4; ++mt)
#pragma unroll
            for (int nt = 0; nt < 5; ++nt)
                acc[mt][nt] = __builtin_amdgcn_mfma_f32_16x16x32_f16(a[mt], bf[nt], acc[mt][nt], 0, 0, 0);
    }
#pragma unroll
    for (int nt = 0; nt < 5; ++nt) {
        int n = w * 80 + nt * 16 + col;
        float bias = Bh[n];
        if (n < 32) {
#pragma unroll
            for (int mt = 0; mt < 4; ++mt)
#pragma unroll
                for (int r = 0; r < 4; ++r) {
                    int i = i0 + mt * 16 + q * 4 + r;
                    Kf[((((size_t)b * 128 + (i >> 5)) * 4 + (n >> 3)) * 32 + (i & 31)) * 8 + (n & 7)]
                        = (_Float16)((acc[mt][nt][r] + bias) * LOG2E);
                }
        } else if (n < 64) {
            int n2 = n - 32;
#pragma unroll
            for (int mt = 0; mt < 4; ++mt)
#pragma unroll
                for (int r = 0; r < 4; ++r) {
                    int j = i0 + mt * 16 + q * 4 + r;
                    Qf[((((size_t)b * 128 + (j >> 5)) * 4 + (n2 >> 3)) * 32 + (j & 31)) * 8 + (n2 & 7)]
                        = (_Float16)(acc[mt][nt][r] + bias);
                }
        } else {
            int c = n - 64;
#pragma unroll
            for (int mt = 0; mt < 4; ++mt) {
                int ib = (i0 >> 4) + mt;
                half4 v4;
#pragma unroll
                for (int r = 0; r < 4; ++r) v4[r] = (_Float16)(acc[mt][nt][r] + bias);
                *(half4*)&Vf[(((size_t)b * 256 + ib) * 256 + c) * 16 + q * 4] = v4;
            }
        }
    }
}

// ---------------- K2: fused attention v8 ------------------------------------
// v6 geometry (512 thr, j-tile 64, grid 512 = 2 blk/CU, 4 waves/SIMD) with
// the i-step widened to 128: Ps buffers are 64j x 128i halfs (16 KB x2) and
// each barrier covers TWO i-64 sub-steps -> barrier count halved (64 -> 32).
// Per-i work, register budget (~90 VGPR), V/K prefetch depth (i64), and the
// XOR swizzle (chunk ^= col&7 on low 3 bits; bit3 = i-half) are unchanged.
// s_setprio(1) wraps the PV MFMA cluster (T5).
#define PS_BUF 8192  /* halfs per Ps buffer (64 x 128, swizzled, 16 KB) */

#define ATTN_SBLK(AK, WO)                                                         \
    {                                                                             \
        floatx4 s = __builtin_amdgcn_mfma_f32_16x16x32_f16(AK, bq, cns, 0, 0, 0); \
        float p0 = exp2f(s[0]);                                                   \
        float p1 = exp2f(s[1]);                                                   \
        float p2 = exp2f(s[2]);                                                   \
        float p3 = exp2f(s[3]);                                                   \
        lacc += (p0 + p1) + (p2 + p3);                                            \
        union { fp16x2 v; uint32_t u; } plo, phi;                                 \
        plo.v = __builtin_amdgcn_cvt_pkrtz(p0, p1);                               \
        phi.v = __builtin_amdgcn_cvt_pkrtz(p2, p3);                               \
        uint2 pw; pw.x = plo.u; pw.y = phi.u;                                     \
        *(uint2*)&PsF[WO] = pw;                                                   \
    }

// One i-64 sub-step. H = which i-half of the NEXT step's S this sub computes.
// COND = (IT < 31): K prefetch + S compute + (for H==1) V prefetch of next step.
// VC = V regs for this sub's PV; VN = V regs being prefetched.
// KKA/KKB = the two k32 chunk indices (0..3) of this sub within the i128 Ps.
#define ATTN_SUB(COND, H, VC, VN, KKA, KKB, ROFF, WOFF)                           \
    {                                                                             \
        if (COND) {                                                               \
            aK0 = *(const half8*)(pK);                                            \
            aK1 = *(const half8*)(pK + 128);                                      \
            pK += 2048;                                                           \
        }                                                                         \
        if ((H) == 0 || (COND)) {                                                 \
            _Pragma("unroll")                                                     \
            for (int ct = 0; ct < 2; ++ct) {                                      \
                VN[ct * 2 + 0] = *(const half8*)(pV0 + ct * 256);                 \
                VN[ct * 2 + 1] = *(const half8*)(pV1 + ct * 256);                 \
            }                                                                     \
            pV0 += 16384; pV1 += 16384;                                           \
        }                                                                         \
        __builtin_amdgcn_s_setprio(1);                                            \
        _Pragma("unroll")                                                         \
        for (int kk = 0; kk < 2; ++kk) {                                          \
            half8 bfr[4];                                                         \
            _Pragma("unroll")                                                     \
            for (int jt = 0; jt < 4; ++jt)                                        \
                bfr[jt] = *(const half8*)&PsF[(ROFF) + jt * 2048 +                \
                    ((kk ? (KKB) : (KKA)) & 1 ? ro1 : ro0) +                      \
                    ((kk ? (KKB) : (KKA)) >> 1) * 64];                            \
            _Pragma("unroll")                                                     \
            for (int ct = 0; ct < 2; ++ct)                                        \
                _Pragma("unroll")                                                 \
                for (int jt = 0; jt < 4; ++jt)                                    \
                    acc[ct][jt] = __builtin_amdgcn_mfma_f32_16x16x32_f16(         \
                        VC[ct * 2 + kk], bfr[jt], acc[ct][jt], 0, 0, 0);          \
        }                                                                         \
        __builtin_amdgcn_s_setprio(0);                                            \
        if (COND) {                                                               \
            ATTN_SBLK(aK0, (WOFF) + wo0 + (H) * 64)                               \
            ATTN_SBLK(aK1, (WOFF) + wo1 + (H) * 64)                               \
        }                                                                         \
    }

#define ATTN_STEP(IT, ROFF, WOFF)                                                 \
    {                                                                             \
        ATTN_SUB((IT) < 31, 0, vA, vB, 0, 1, ROFF, WOFF)                          \
        ATTN_SUB((IT) < 31, 1, vB, vA, 2, 3, ROFF, WOFF)                          \
        asm volatile("s_waitcnt lgkmcnt(0)\n\ts_barrier" ::: "memory");           \
    }

__global__ __launch_bounds__(512, 4) void k_attn(const _Float16* __restrict__ Kf,
                                                 const _Float16* __restrict__ Qf,
                                                 const _Float16* __restrict__ Vf,
                                                 const float* __restrict__ x,
                                                 const float* __restrict__ gptr,
                                                 float* __restrict__ out) {
    __shared__ _Float16 PsF[2 * PS_BUF] __attribute__((aligned(16)));  // 32,768 B
    __shared__ float Lp[2][64];
    int id = blockIdx.x;
    int b  = id & 7;            // XCD-local batch
    int j0 = (id >> 3) * 64;
    int t = threadIdx.x;
    int w = t >> 6, lane = t & 63, col = lane & 15, q = lane >> 4;
    int jts = w & 3, ihs = w >> 2;   // S role
    int cw  = w * 32;                // PV c-strip
    const _Float16* Kfb = Kf + (size_t)b * 131072;
    const _Float16* Qfb = Qf + (size_t)b * 131072;
    const _Float16* Vfb = Vf + (size_t)b * 1048576;
    // ---- per-lane invariant pointers / offsets
    const _Float16* pK  = Kfb + ((ihs * 4 + q) * 32 + col) * 8;          // +2048 per i64 sub
    const _Float16* pV0 = Vfb + ((q >> 1) * 256 + cw + col) * 16 + (q & 1) * 8;  // +16384 per i64 sub
    const _Float16* pV1 = pV0 + 8192;                                    // kk odd
    // ---- swizzled Ps offsets (half units; row = 128 halfs = 256 B, chunk = 8 halfs)
    // read  (PV B-frag): row j = jt*16+col, chunk = (KK*4 + q) ^low3 (col&7), KK 0..3
    // write (S uint2)  : row j = jts*16+col, chunk = H*8 + (ihs*4 + itl*2 + (q>>1)) ^low3 (col&7)
    const int cswz = col & 7;
    const int ro0 = col * 128 + ((q ^ cswz) << 3);       // KK even (bit2 of chunk clear)
    const int ro1 = ro0 ^ 32;                            // KK odd  (chunk bit2)
    const int wo0 = (jts * 16 + col) * 128 + ((((ihs << 2) + (q >> 1)) ^ cswz) << 3) + (q & 1) * 4;
    const int wo1 = wo0 ^ 16;                            // itl = 1 (chunk bit1)
    const floatx4 cns = {NSHIFT_L2E, NSHIFT_L2E, NSHIFT_L2E, NSHIFT_L2E};
    floatx4 acc[2][4];
#pragma unroll
    for (int ct = 0; ct < 2; ++ct)
#pragma unroll
        for (int jt = 0; jt < 4; ++jt) acc[ct][jt] = (floatx4){0.f, 0.f, 0.f, 0.f};
    float lacc = 0.f;
    half8 vA[4], vB[4], aK0, aK1;
    // ---- prologue: V(0,h0) -> vA; K(0) both halves; S(0) -> buf0; Q
#pragma unroll
    for (int ct = 0; ct < 2; ++ct) {
        vA[ct * 2 + 0] = *(const half8*)(pV0 + ct * 256);
        vA[ct * 2 + 1] = *(const half8*)(pV1 + ct * 256);
    }
    pV0 += 16384; pV1 += 16384;
    int jj = j0 + jts * 16;
    half8 bq = *(const half8*)&Qfb[(((jj >> 5) * 4 + q) * 32 + ((jj & 31) + col)) * 8];
#pragma unroll
    for (int h = 0; h < 2; ++h) {
        aK0 = *(const half8*)(pK);
        aK1 = *(const half8*)(pK + 128);
        pK += 2048;
        ATTN_SBLK(aK0, wo0 + h * 64)
        ATTN_SBLK(aK1, wo1 + h * 64)
    }
    asm volatile("s_waitcnt lgkmcnt(0)\n\ts_barrier" ::: "memory");
    // ---- main loop: 32 i128-steps, unrolled by 2 (one relaxed barrier per step)
    for (int m = 0; m < 16; ++m) {
        int it = m * 2;
        ATTN_STEP(it,     0,      PS_BUF)
        ATTN_STEP(it + 1, PS_BUF, 0)
    }
    // ---- l finalize
    lacc += __shfl_xor(lacc, 16, 64);
    lacc += __shfl_xor(lacc, 32, 64);
    if (lane < 16) Lp[ihs][jts * 16 + lane] = lacc;
    __syncthreads();
    float gamma = gptr[0];
    const float* xb = x + (size_t)b * C_ * N_;
    float* ob = out + (size_t)b * C_ * N_;
#pragma unroll
    for (int jt = 0; jt < 4; ++jt) {
        int jl = jt * 16 + col;
        float li = 1.0f / (Lp[0][jl] + Lp[1][jl]);
        int j = j0 + jl;
#pragma unroll
        for (int ct = 0; ct < 2; ++ct)
#pragma unroll
            for (int r = 0; r < 4; ++r) {
                int c = cw + ct * 16 + q * 4 + r;
                size_t off = (size_t)c * N_ + j;
                ob[off] = gamma * acc[ct][jt][r] * li + xb[off];
            }
    }
}

extern "C" void kernel_launch(void* const* d_in, const int* in_sizes, int n_in,
                              void* d_out, int out_size, void* d_ws, size_t ws_size,
                              hipStream_t stream) {
    const float* x  = (const float*)d_in[0];
    const float* wq = (const float*)d_in[1];
    const float* bq = (const float*)d_in[2];
    const float* wk = (const float*)d_in[3];
    const float* bk = (const float*)d_in[4];
    const float* wv = (const float*)d_in[5];
    const float* bv = (const float*)d_in[6];
    const float* gm = (const float*)d_in[7];
    float* out = (float*)d_out;
    char* ws = (char*)d_ws;
    // workspace layout (~21.1 MB)
    _Float16* Vf  = (_Float16*)ws;                    // 16,777,216 B
    _Float16* Kf  = (_Float16*)(ws + 16777216);       //  2,097,152 B
    _Float16* Qf  = (_Float16*)(ws + 18874368);       //  2,097,152 B
    _Float16* Whf = (_Float16*)(ws + 20971520);       //    163,840 B
    float*    Bh  = (float*)(ws + 21135360);          //      1,280 B

    k_wprep<<<dim3(320), 256, 0, stream>>>(wq, bq, wk, bk, wv, bv, Whf, Bh);
    k_proj<<<dim3(512), 256, 0, stream>>>(x, Whf, Bh, Kf, Qf, Vf);
    k_attn<<<dim3(512), 512, 0, stream>>>(Kf, Qf, Vf, x, gm, out);
}

// Round 6
// 190.368 us; speedup vs baseline: 1.0947x; 1.0029x over previous
//
#include <hip/hip_runtime.h>
#include <stdint.h>

#define B_ 8
#define C_ 256
#define N_ 4096
#define LOG2E 1.44269504088896f
#define NSHIFT_L2E (-14.0f * 1.44269504088896f)   // exp(s-14) = exp2(s*log2e - 14*log2e)

typedef _Float16 half8 __attribute__((ext_vector_type(8)));
typedef _Float16 half4 __attribute__((ext_vector_type(4)));
typedef __fp16  fp16x2 __attribute__((ext_vector_type(2)));
typedef float floatx4 __attribute__((ext_vector_type(4)));

// ---------------- K0: weights -> fragment-ordered fp16 Whf + Bh -------------
__global__ __launch_bounds__(256) void k_wprep(const float* __restrict__ wq, const float* __restrict__ bq,
                                               const float* __restrict__ wk, const float* __restrict__ bk,
                                               const float* __restrict__ wv, const float* __restrict__ bv,
                                               _Float16* __restrict__ Whf, float* __restrict__ Bh) {
    int r = blockIdx.x;   // n: 0..319
    int t = threadIdx.x;  // k: 0..255
    const float* src;
    float bias;
    if (r < 32)      { src = wq + r * 256;        bias = bq[r]; }
    else if (r < 64) { src = wk + (r - 32) * 256; bias = bk[r - 32]; }
    else             { src = wv + (r - 64) * 256; bias = bv[r - 64]; }
    Whf[(t >> 3) * 2560 + r * 8 + (t & 7)] = (_Float16)src[t];
    if (t == 0) Bh[r] = bias;
}

// ---------------- K1: fused transpose + projection GEMM ---------------------
//   Kf[b][i>>5][k>>3][i&31][k&7]  (k = n)   PRE-SCALED by LOG2E      2 MB
//   Qf[b][j>>5][k>>3][j&31][k&7]  (k = n-32)                         2 MB
//   Vf[b][i>>4][c][i&15]          (c = n-64)                        16.8 MB
__global__ __launch_bounds__(256) void k_proj(const float* __restrict__ x,
                                              const _Float16* __restrict__ Whf,
                                              const float* __restrict__ Bh,
                                              _Float16* __restrict__ Kf,
                                              _Float16* __restrict__ Qf,
                                              _Float16* __restrict__ Vf) {
    __shared__ float xtile[64 * 65];                                 // 16,640 B
    __shared__ _Float16 As[64 * 264] __attribute__((aligned(16)));   // 33,792 B
    int id = blockIdx.x;
    int b  = id & 7;          // XCD-local batch
    int i0 = (id >> 3) * 64;
    int t = threadIdx.x;
    int w = t >> 6, lane = t & 63, col = lane & 15, q = lane >> 4;
    const float* xb = x + (size_t)b * C_ * N_ + i0;
    for (int cc = 0; cc < 4; ++cc) {
        int cr = t >> 4;
        int ip = (t & 15) * 4;
#pragma unroll
        for (int k = 0; k < 4; ++k)
            *(float4*)&xtile[(cr + 16 * k) * 65 + ip] =
                *(const float4*)&xb[(size_t)(cc * 64 + cr + 16 * k) * N_ + ip];
        __syncthreads();
        int i = t & 63, cb2 = (t >> 6) * 16;
        float v[16];
#pragma unroll
        for (int k = 0; k < 16; ++k) v[k] = xtile[(cb2 + k) * 65 + i];
        half8 h0, h1;
#pragma unroll
        for (int k = 0; k < 8; ++k) { h0[k] = (_Float16)v[k]; h1[k] = (_Float16)v[8 + k]; }
        *(half8*)&As[i * 264 + cc * 64 + cb2] = h0;
        *(half8*)&As[i * 264 + cc * 64 + cb2 + 8] = h1;
        __syncthreads();
    }
    floatx4 acc[4][5];
#pragma unroll
    for (int mt = 0; mt < 4; ++mt)
#pragma unroll
        for (int nt = 0; nt < 5; ++nt) acc[mt][nt] = (floatx4){0.f, 0.f, 0.f, 0.f};
    for (int kc = 0; kc < 8; ++kc) {
        half8 a[4], bf[5];
#pragma unroll
        for (int nt = 0; nt < 5; ++nt)
            bf[nt] = *(const half8*)&Whf[(kc * 4 + q) * 2560 + (w * 80 + nt * 16 + col) * 8];
#pragma unroll
        for (int mt = 0; mt < 4; ++mt)
            a[mt] = *(const half8*)&As[(mt * 16 + col) * 264 + kc * 32 + q * 8];
#pragma unroll
        for (int mt = 0; mt < 4; ++mt)
#pragma unroll
            for (int nt = 0; nt < 5; ++nt)
                acc[mt][nt] = __builtin_amdgcn_mfma_f32_16x16x32_f16(a[mt], bf[nt], acc[mt][nt], 0, 0, 0);
    }
#pragma unroll
    for (int nt = 0; nt < 5; ++nt) {
        int n = w * 80 + nt * 16 + col;
        float bias = Bh[n];
        if (n < 32) {
#pragma unroll
            for (int mt = 0; mt < 4; ++mt)
#pragma unroll
                for (int r = 0; r < 4; ++r) {
                    int i = i0 + mt * 16 + q * 4 + r;
                    Kf[((((size_t)b * 128 + (i >> 5)) * 4 + (n >> 3)) * 32 + (i & 31)) * 8 + (n & 7)]
                        = (_Float16)((acc[mt][nt][r] + bias) * LOG2E);
                }
        } else if (n < 64) {
            int n2 = n - 32;
#pragma unroll
            for (int mt = 0; mt < 4; ++mt)
#pragma unroll
                for (int r = 0; r < 4; ++r) {
                    int j = i0 + mt * 16 + q * 4 + r;
                    Qf[((((size_t)b * 128 + (j >> 5)) * 4 + (n2 >> 3)) * 32 + (j & 31)) * 8 + (n2 & 7)]
                        = (_Float16)(acc[mt][nt][r] + bias);
                }
        } else {
            int c = n - 64;
#pragma unroll
            for (int mt = 0; mt < 4; ++mt) {
                int ib = (i0 >> 4) + mt;
                half4 v4;
#pragma unroll
                for (int r = 0; r < 4; ++r) v4[r] = (_Float16)(acc[mt][nt][r] + bias);
                *(half4*)&Vf[(((size_t)b * 256 + ib) * 256 + c) * 16 + q * 4] = v4;
            }
        }
    }
}

// ---------------- K2: fused attention v9 ------------------------------------
// v6 geometry (512 thr, j-tile 64, grid 512 = 2 blk/CU, 4 waves/SIMD) and the
// verified conflict-free 64x64 swizzled Ps, but with S taken OFF the barrier
// critical path:
//   - 4 Ps buffers (mod-4 cycle, 32 KB): at step t, waves READ P(t) from
//     buf[t&3] and WRITE S(t+2) to buf[(t+2)&3] -> every write has 2 barriers
//     of slack before its readers.
//   - K prefetch distance 2: K(t+3) issued at step t, consumed (for S(t+2))
//     with a full step of latency slack.
//   - V register ping-pong distance 1 (unchanged).
// Relaxed lgkm-only barrier (V/K global prefetches stay in flight).
#define PS_BUF 4096  /* halfs per Ps buffer (64 x 64, swizzled, 8 KB) */

#define ATTN_SBLK(AK, WO)                                                         \
    {                                                                             \
        floatx4 s = __builtin_amdgcn_mfma_f32_16x16x32_f16(AK, bq, cns, 0, 0, 0); \
        float p0 = exp2f(s[0]);                                                   \
        float p1 = exp2f(s[1]);                                                   \
        float p2 = exp2f(s[2]);                                                   \
        float p3 = exp2f(s[3]);                                                   \
        lacc += (p0 + p1) + (p2 + p3);                                            \
        union { fp16x2 v; uint32_t u; } plo, phi;                                 \
        plo.v = __builtin_amdgcn_cvt_pkrtz(p0, p1);                               \
        phi.v = __builtin_amdgcn_cvt_pkrtz(p2, p3);                               \
        uint2 pw; pw.x = plo.u; pw.y = phi.u;                                     \
        *(uint2*)&PsF[WO] = pw;                                                   \
    }

// One i64 step. DO_V: prefetch V(t+1); DO_K: prefetch K(t+3); DO_S: compute
// and store S(t+2) from KC* (loaded 1 step ago). RB/WB: literal buffer bases.
#define ATTN_STEP(DO_V, DO_K, DO_S, VCUR, VNXT, KC0, KC1, KN0, KN1, RB, WB)       \
    {                                                                             \
        if (DO_V) {                                                               \
            _Pragma("unroll")                                                     \
            for (int ct = 0; ct < 2; ++ct) {                                      \
                VNXT[ct * 2 + 0] = *(const half8*)(pV0 + ct * 256);               \
                VNXT[ct * 2 + 1] = *(const half8*)(pV1 + ct * 256);               \
            }                                                                     \
            pV0 += 16384; pV1 += 16384;                                           \
        }                                                                         \
        if (DO_K) {                                                               \
            KN0 = *(const half8*)(pK);                                            \
            KN1 = *(const half8*)(pK + 128);                                      \
            pK += 2048;                                                           \
        }                                                                         \
        __builtin_amdgcn_s_setprio(1);                                            \
        _Pragma("unroll")                                                         \
        for (int kk = 0; kk < 2; ++kk) {                                          \
            half8 bfr[4];                                                         \
            _Pragma("unroll")                                                     \
            for (int jt = 0; jt < 4; ++jt)                                        \
                bfr[jt] = *(const half8*)&PsF[(RB) + jt * 1024 + (kk ? ro1 : ro0)]; \
            _Pragma("unroll")                                                     \
            for (int ct = 0; ct < 2; ++ct)                                        \
                _Pragma("unroll")                                                 \
                for (int jt = 0; jt < 4; ++jt)                                    \
                    acc[ct][jt] = __builtin_amdgcn_mfma_f32_16x16x32_f16(         \
                        VCUR[ct * 2 + kk], bfr[jt], acc[ct][jt], 0, 0, 0);        \
        }                                                                         \
        __builtin_amdgcn_s_setprio(0);                                            \
        if (DO_S) {                                                               \
            ATTN_SBLK(KC0, (WB) + wo0)                                            \
            ATTN_SBLK(KC1, (WB) + wo1)                                            \
        }                                                                         \
        asm volatile("s_waitcnt lgkmcnt(0)\n\ts_barrier" ::: "memory");           \
    }

__global__ __launch_bounds__(512, 4) void k_attn(const _Float16* __restrict__ Kf,
                                                 const _Float16* __restrict__ Qf,
                                                 const _Float16* __restrict__ Vf,
                                                 const float* __restrict__ x,
                                                 const float* __restrict__ gptr,
                                                 float* __restrict__ out) {
    __shared__ _Float16 PsF[4 * PS_BUF] __attribute__((aligned(16)));  // 32,768 B
    __shared__ float Lp[2][64];
    int id = blockIdx.x;
    int b  = id & 7;            // XCD-local batch
    int j0 = (id >> 3) * 64;
    int t = threadIdx.x;
    int w = t >> 6, lane = t & 63, col = lane & 15, q = lane >> 4;
    int jts = w & 3, ihs = w >> 2;   // S role
    int cw  = w * 32;                // PV c-strip
    const _Float16* Kfb = Kf + (size_t)b * 131072;
    const _Float16* Qfb = Qf + (size_t)b * 131072;
    const _Float16* Vfb = Vf + (size_t)b * 1048576;
    // ---- per-lane invariant pointers / offsets
    const _Float16* pK  = Kfb + ((ihs * 4 + q) * 32 + col) * 8;          // +2048 per i64
    const _Float16* pV0 = Vfb + ((q >> 1) * 256 + cw + col) * 16 + (q & 1) * 8;  // +16384 per i64
    const _Float16* pV1 = pV0 + 8192;                                    // kk=1
    // ---- swizzled Ps offsets (v6-verified: row = 64 halfs = 128 B, chunk = 8 halfs)
    // read  (PV B-frag): row j = jt*16+col, chunk = (kk*4 + q) ^ (col&7)
    // write (S uint2)  : row j = jts*16+col, chunk = ihs*4 ^ itl*2 ^ (q>>1) ^ (col&7)
    const int cswz = col & 7;
    const int ro0 = col * 64 + ((q ^ cswz) << 3);        // kk = 0
    const int ro1 = ro0 ^ 32;                            // kk = 1 (chunk bit2)
    const int wo0 = (jts * 16 + col) * 64 + (((ihs << 2) ^ (q >> 1) ^ cswz) << 3) + (q & 1) * 4;
    const int wo1 = wo0 ^ 16;                            // itl = 1 (chunk bit1)
    const floatx4 cns = {NSHIFT_L2E, NSHIFT_L2E, NSHIFT_L2E, NSHIFT_L2E};
    floatx4 acc[2][4];
#pragma unroll
    for (int ct = 0; ct < 2; ++ct)
#pragma unroll
        for (int jt = 0; jt < 4; ++jt) acc[ct][jt] = (floatx4){0.f, 0.f, 0.f, 0.f};
    float lacc = 0.f;
    half8 vA[4], vB[4], kA0, kA1, kB0, kB1;
    // ---- prologue: V(0)->vA; Q; S(0)->buf0, S(1)->buf1; K(2)->kA
#pragma unroll
    for (int ct = 0; ct < 2; ++ct) {
        vA[ct * 2 + 0] = *(const half8*)(pV0 + ct * 256);
        vA[ct * 2 + 1] = *(const half8*)(pV1 + ct * 256);
    }
    pV0 += 16384; pV1 += 16384;
    int jj = j0 + jts * 16;
    half8 bq = *(const half8*)&Qfb[(((jj >> 5) * 4 + q) * 32 + ((jj & 31) + col)) * 8];
    kA0 = *(const half8*)(pK);           // K(0)
    kA1 = *(const half8*)(pK + 128);
    pK += 2048;
    ATTN_SBLK(kA0, 0 * PS_BUF + wo0)
    ATTN_SBLK(kA1, 0 * PS_BUF + wo1)
    kA0 = *(const half8*)(pK);           // K(1)
    kA1 = *(const half8*)(pK + 128);
    pK += 2048;
    ATTN_SBLK(kA0, 1 * PS_BUF + wo0)
    ATTN_SBLK(kA1, 1 * PS_BUF + wo1)
    kA0 = *(const half8*)(pK);           // K(2) -> consumed at step 0
    kA1 = *(const half8*)(pK + 128);
    pK += 2048;
    asm volatile("s_waitcnt lgkmcnt(0)\n\ts_barrier" ::: "memory");
    // ---- main loop: t = 0..59 (all flags on), unrolled by 4 for buffer imms
    for (int m = 0; m < 15; ++m) {
        ATTN_STEP(1, 1, 1, vA, vB, kA0, kA1, kB0, kB1, 0 * PS_BUF, 2 * PS_BUF)
        ATTN_STEP(1, 1, 1, vB, vA, kB0, kB1, kA0, kA1, 1 * PS_BUF, 3 * PS_BUF)
        ATTN_STEP(1, 1, 1, vA, vB, kA0, kA1, kB0, kB1, 2 * PS_BUF, 0 * PS_BUF)
        ATTN_STEP(1, 1, 1, vB, vA, kB0, kB1, kA0, kA1, 3 * PS_BUF, 1 * PS_BUF)
    }
    // ---- peeled tail: t = 60..63
    ATTN_STEP(1, 1, 1, vA, vB, kA0, kA1, kB0, kB1, 0 * PS_BUF, 2 * PS_BUF)  // t=60: K(63), S(62)
    ATTN_STEP(1, 0, 1, vB, vA, kB0, kB1, kA0, kA1, 1 * PS_BUF, 3 * PS_BUF)  // t=61: S(63) from K(63)
    ATTN_STEP(1, 0, 0, vA, vB, kA0, kA1, kB0, kB1, 2 * PS_BUF, 0 * PS_BUF)  // t=62: V(63)
    ATTN_STEP(0, 0, 0, vB, vA, kB0, kB1, kA0, kA1, 3 * PS_BUF, 1 * PS_BUF)  // t=63
    // ---- l finalize
    lacc += __shfl_xor(lacc, 16, 64);
    lacc += __shfl_xor(lacc, 32, 64);
    if (lane < 16) Lp[ihs][jts * 16 + lane] = lacc;
    __syncthreads();
    float gamma = gptr[0];
    const float* xb = x + (size_t)b * C_ * N_;
    float* ob = out + (size_t)b * C_ * N_;
#pragma unroll
    for (int jt = 0; jt < 4; ++jt) {
        int jl = jt * 16 + col;
        float li = 1.0f / (Lp[0][jl] + Lp[1][jl]);
        int j = j0 + jl;
#pragma unroll
        for (int ct = 0; ct < 2; ++ct)
#pragma unroll
            for (int r = 0; r < 4; ++r) {
                int c = cw + ct * 16 + q * 4 + r;
                size_t off = (size_t)c * N_ + j;
                ob[off] = gamma * acc[ct][jt][r] * li + xb[off];
            }
    }
}

extern "C" void kernel_launch(void* const* d_in, const int* in_sizes, int n_in,
                              void* d_out, int out_size, void* d_ws, size_t ws_size,
                              hipStream_t stream) {
    const float* x  = (const float*)d_in[0];
    const float* wq = (const float*)d_in[1];
    const float* bq = (const float*)d_in[2];
    const float* wk = (const float*)d_in[3];
    const float* bk = (const float*)d_in[4];
    const float* wv = (const float*)d_in[5];
    const float* bv = (const float*)d_in[6];
    const float* gm = (const float*)d_in[7];
    float* out = (float*)d_out;
    char* ws = (char*)d_ws;
    // workspace layout (~21.1 MB)
    _Float16* Vf  = (_Float16*)ws;                    // 16,777,216 B
    _Float16* Kf  = (_Float16*)(ws + 16777216);       //  2,097,152 B
    _Float16* Qf  = (_Float16*)(ws + 18874368);       //  2,097,152 B
    _Float16* Whf = (_Float16*)(ws + 20971520);       //    163,840 B
    float*    Bh  = (float*)(ws + 21135360);          //      1,280 B

    k_wprep<<<dim3(320), 256, 0, stream>>>(wq, bq, wk, bk, wv, bv, Whf, Bh);
    k_proj<<<dim3(512), 256, 0, stream>>>(x, Whf, Bh, Kf, Qf, Vf);
    k_attn<<<dim3(512), 512, 0, stream>>>(Kf, Qf, Vf, x, gm, out);
}